// Round 1
// baseline (701.377 us; speedup 1.0000x reference)
//
#include <hip/hip_runtime.h>
#include <hip/hip_bf16.h>

// Problem constants (fixed by reference): B=16, C=48, H=W=64, N_CORR=2048
#define BB 16
#define C_DIM 48
#define HW 4096            // 64*64
#define W_DIM 64
#define NCORR 2048
#define QT 128             // queries per block in maxscore
#define NT 128             // db columns staged per LDS tile
#define LDS_STRIDE 52      // 52 floats = 208 B: 16B-aligned for ds_read_b128, breaks pow2 banks

// ---------------------------------------------------------------------------
// Kernel 1: reciprocal column norms for both feature maps.
// rn[b*HW + p] = 1 / max(||x[b, :, p]||, 1e-12)
// ---------------------------------------------------------------------------
__global__ void rnorm_kernel(const float* __restrict__ x1,
                             const float* __restrict__ x2,
                             float* __restrict__ rn1,
                             float* __restrict__ rn2) {
    int gid = blockIdx.x * 256 + threadIdx.x;   // [0, 2*B*HW)
    int which = gid >> 16;                      // B*HW = 65536
    int rem = gid & 65535;
    int b = rem >> 12;
    int p = rem & (HW - 1);
    const float* x = which ? x2 : x1;
    float* rn = which ? rn2 : rn1;
    const float* col = x + (size_t)b * C_DIM * HW + p;
    float s = 0.f;
#pragma unroll
    for (int c = 0; c < C_DIM; ++c) {
        float v = col[c * HW];
        s = fmaf(v, v, s);
    }
    rn[b * HW + p] = 1.f / fmaxf(sqrtf(s), 1e-12f);
}

// ---------------------------------------------------------------------------
// Kernel 2: positive distances. pos[b*N + n] = 2 - 2 * d1n . d2n
// ---------------------------------------------------------------------------
__global__ void pos_kernel(const float* __restrict__ x1,
                           const float* __restrict__ x2,
                           const float* __restrict__ rn1,
                           const float* __restrict__ rn2,
                           const int* __restrict__ ids,
                           const int* __restrict__ fp2,
                           float* __restrict__ pos) {
    int gid = blockIdx.x * 256 + threadIdx.x;   // [0, B*NCORR)
    int b = gid >> 11;
    int n = gid & (NCORR - 1);
    int col1 = ids[b * NCORR + n];
    int i2 = fp2[b * 2 * NCORR + n];
    int j2 = fp2[b * 2 * NCORR + NCORR + n];
    int col2 = i2 * W_DIM + j2;
    const float* a = x1 + (size_t)b * C_DIM * HW + col1;
    const float* bp = x2 + (size_t)b * C_DIM * HW + col2;
    float dot = 0.f;
#pragma unroll
    for (int c = 0; c < C_DIM; ++c) {
        dot = fmaf(a[c * HW], bp[c * HW], dot);
    }
    dot *= rn1[b * HW + col1] * rn2[b * HW + col2];
    pos[gid] = 2.f - 2.f * dot;
}

// ---------------------------------------------------------------------------
// Kernel 3: masked hardest-negative search (the hot kernel).
// grid = (2048/QT, B, 2); block = 256.
// dir 0: queries = d1 (cols ids of img1), db = img2, mask anchor = fp2.
// dir 1: queries = d2 (cols fp2 of img2), db = img1, mask anchor = pos(ids).
// Writes maxs[(dir*B + b)*NCORR + n] = max over allowed m of q_n . db_m
// ---------------------------------------------------------------------------
__global__ __launch_bounds__(256, 2) void maxscore_kernel(
    const float* __restrict__ x1, const float* __restrict__ x2,
    const float* __restrict__ rn1, const float* __restrict__ rn2,
    const int* __restrict__ ids, const int* __restrict__ fp2,
    float* __restrict__ maxs) {
    __shared__ float db[NT * LDS_STRIDE];   // 26,624 B
    __shared__ float red[4][QT];            // 2 KB cross-wave max reduce

    int tid = threadIdx.x;
    int wave = tid >> 6;
    int lane = tid & 63;
    int b = blockIdx.y;
    int dir = blockIdx.z;
    int tile = blockIdx.x;

    const float* qf;  const float* rq;
    const float* dbf; const float* rdb;
    if (dir == 0) {
        qf = x1 + (size_t)b * C_DIM * HW;  rq = rn1 + b * HW;
        dbf = x2 + (size_t)b * C_DIM * HW; rdb = rn2 + b * HW;
    } else {
        qf = x2 + (size_t)b * C_DIM * HW;  rq = rn2 + b * HW;
        dbf = x1 + (size_t)b * C_DIM * HW; rdb = rn1 + b * HW;
    }

    // Two queries per lane: tile-local indices lane and lane+64.
    int qcol[2], qi[2], qj[2];
#pragma unroll
    for (int k = 0; k < 2; ++k) {
        int n = tile * QT + lane + k * 64;
        int idv = ids[b * NCORR + n];
        int i2 = fp2[b * 2 * NCORR + n];
        int j2 = fp2[b * 2 * NCORR + NCORR + n];
        if (dir == 0) { qcol[k] = idv;              qi[k] = i2;       qj[k] = j2; }
        else          { qcol[k] = i2 * W_DIM + j2;  qi[k] = idv >> 6; qj[k] = idv & 63; }
    }

    float qreg[2][C_DIM];
#pragma unroll
    for (int k = 0; k < 2; ++k) {
        float r = rq[qcol[k]];
#pragma unroll
        for (int c = 0; c < C_DIM; ++c) {
            qreg[k][c] = qf[c * HW + qcol[k]] * r;
        }
    }

    float mx0 = -1e30f, mx1 = -1e30f;

    for (int t = 0; t < HW / NT; ++t) {     // 32 tiles
        __syncthreads();
        // Stage NT columns x C_DIM (coalesced global reads, normalized on the fly)
#pragma unroll
        for (int u = 0; u < (NT * C_DIM) / 256; ++u) {  // 24 iters
            int idx = u * 256 + tid;
            int c = idx >> 7;           // idx / NT
            int mm = idx & (NT - 1);
            int m = t * NT + mm;
            db[mm * LDS_STRIDE + c] = dbf[c * HW + m] * rdb[m];
        }
        __syncthreads();

        int mbase = wave * (NT / 4);
        for (int mmi = 0; mmi < NT / 4; ++mmi) {   // 32 cols per wave
            int mm = mbase + mmi;
            int m = t * NT + mm;
            int mi = m >> 6, mj = m & 63;
            const float* dcol = &db[mm * LDS_STRIDE];
            float acc0 = 0.f, acc1 = 0.f;
#pragma unroll
            for (int c = 0; c < C_DIM; ++c) {
                float dv = dcol[c];                 // wave-uniform broadcast
                acc0 = fmaf(qreg[0][c], dv, acc0);
                acc1 = fmaf(qreg[1][c], dv, acc1);
            }
            int di0 = qi[0] - mi; di0 = di0 < 0 ? -di0 : di0;
            int dj0 = qj[0] - mj; dj0 = dj0 < 0 ? -dj0 : dj0;
            int di1 = qi[1] - mi; di1 = di1 < 0 ? -di1 : di1;
            int dj1 = qj[1] - mj; dj1 = dj1 < 0 ? -dj1 : dj1;
            int ch0 = di0 > dj0 ? di0 : dj0;
            int ch1 = di1 > dj1 ? di1 : dj1;
            mx0 = fmaxf(mx0, ch0 > 4 ? acc0 : -1e30f);
            mx1 = fmaxf(mx1, ch1 > 4 ? acc1 : -1e30f);
        }
    }

    // Cross-wave max reduce
    red[wave][lane] = mx0;
    red[wave][lane + 64] = mx1;
    __syncthreads();
    if (tid < QT) {
        float m0 = red[0][tid];
        m0 = fmaxf(m0, red[1][tid]);
        m0 = fmaxf(m0, red[2][tid]);
        m0 = fmaxf(m0, red[3][tid]);
        int n = tile * QT + tid;
        maxs[((size_t)dir * BB + b) * NCORR + n] = m0;
    }
}

// ---------------------------------------------------------------------------
// Kernel 4: per-image weighted loss. grid = B blocks of 256.
// ---------------------------------------------------------------------------
__global__ void loss_kernel(const float* __restrict__ att1,
                            const float* __restrict__ att2,
                            const int* __restrict__ ids,
                            const int* __restrict__ fp2,
                            const float* __restrict__ maxs,
                            const float* __restrict__ pos,
                            float* __restrict__ perimg) {
    int b = blockIdx.x;
    int tid = threadIdx.x;
    float num = 0.f, den = 0.f;
    for (int n = tid; n < NCORR; n += 256) {
        float ms = fmaxf(maxs[b * NCORR + n], maxs[(BB + b) * NCORR + n]);
        float minneg = 2.f - 2.f * ms;          // min(neg1, neg2)
        float diff = pos[b * NCORR + n] - minneg;
        int idv = ids[b * NCORR + n];
        int i2 = fp2[b * 2 * NCORR + n];
        int j2 = fp2[b * 2 * NCORR + NCORR + n];
        float w = att1[b * HW + idv] * att2[b * HW + i2 * W_DIM + j2];
        num += w * fmaxf(0.f, 1.f + diff);
        den += w;
    }
    __shared__ float sn[256], sd[256];
    sn[tid] = num; sd[tid] = den;
    __syncthreads();
    for (int s = 128; s > 0; s >>= 1) {
        if (tid < s) { sn[tid] += sn[tid + s]; sd[tid] += sd[tid + s]; }
        __syncthreads();
    }
    if (tid == 0) perimg[b] = sn[0] / sd[0];
}

// ---------------------------------------------------------------------------
// Kernel 5: mean over images -> d_out[0]
// ---------------------------------------------------------------------------
__global__ void final_kernel(const float* __restrict__ perimg,
                             float* __restrict__ out) {
    float v = (threadIdx.x < BB) ? perimg[threadIdx.x] : 0.f;
#pragma unroll
    for (int off = 32; off > 0; off >>= 1) v += __shfl_down(v, off, 64);
    if (threadIdx.x == 0) out[0] = v * (1.f / BB);
}

extern "C" void kernel_launch(void* const* d_in, const int* in_sizes, int n_in,
                              void* d_out, int out_size, void* d_ws, size_t ws_size,
                              hipStream_t stream) {
    const float* x1  = (const float*)d_in[0];
    const float* x2  = (const float*)d_in[1];
    const float* att1 = (const float*)d_in[2];
    const float* att2 = (const float*)d_in[3];
    const int* ids   = (const int*)d_in[4];
    const int* fp2   = (const int*)d_in[5];
    float* out = (float*)d_out;

    // Workspace layout (floats): everything rewritten every call.
    float* w = (float*)d_ws;
    float* rn1    = w;                 // B*HW            = 65536
    float* rn2    = w + 65536;         // B*HW            = 65536
    float* maxs   = w + 131072;        // 2*B*NCORR       = 65536
    float* pos    = w + 196608;        // B*NCORR         = 32768
    float* perimg = w + 229376;        // B               = 16

    rnorm_kernel<<<dim3(2 * BB * HW / 256), dim3(256), 0, stream>>>(x1, x2, rn1, rn2);
    pos_kernel<<<dim3(BB * NCORR / 256), dim3(256), 0, stream>>>(x1, x2, rn1, rn2, ids, fp2, pos);
    maxscore_kernel<<<dim3(NCORR / QT, BB, 2), dim3(256), 0, stream>>>(
        x1, x2, rn1, rn2, ids, fp2, maxs);
    loss_kernel<<<dim3(BB), dim3(256), 0, stream>>>(att1, att2, ids, fp2, maxs, pos, perimg);
    final_kernel<<<dim3(1), dim3(64), 0, stream>>>(perimg, out);
}

// Round 2
// 198.837 us; speedup vs baseline: 3.5274x; 3.5274x over previous
//
#include <hip/hip_runtime.h>
#include <stdint.h>

// Problem constants: B=16, C=48, H=W=64, N_CORR=2048
#define BB 16
#define HW 4096
#define NC 2048
#define KHW 72           // halfwords per column: 48 data + 16 zeros (K-pad to 64) + 8 pad
#define KB 144           // bytes per column (16B-aligned, stride 36 words: conflict-benign)

typedef __attribute__((ext_vector_type(8))) __bf16 bf16x8;
typedef __attribute__((ext_vector_type(8))) short short8;
typedef __attribute__((ext_vector_type(4))) float floatx4;

static __device__ __forceinline__ unsigned short f2bf(float f) {
    unsigned u = __builtin_bit_cast(unsigned, f);
    unsigned r = u + 0x7fffu + ((u >> 16) & 1u);    // RNE
    return (unsigned short)(r >> 16);
}

#define GLD16(g, l) __builtin_amdgcn_global_load_lds((const __attribute__((address_space(1))) void*)(g), (__attribute__((address_space(3))) void*)(l), 16, 0, 0)
#define GLD4(g, l)  __builtin_amdgcn_global_load_lds((const __attribute__((address_space(1))) void*)(g), (__attribute__((address_space(3))) void*)(l), 4, 0, 0)

// ---------------------------------------------------------------------------
// prep_db: normalize every column of x1,x2 to bf16, K-padded, stride 144B.
// Also writes rn (reciprocal norms) for prep_q. Thread = one (img,b,col).
// ---------------------------------------------------------------------------
__global__ void prep_db(const float* __restrict__ x1, const float* __restrict__ x2,
                        unsigned short* __restrict__ dbp, float* __restrict__ rn) {
    int gid = blockIdx.x * 256 + threadIdx.x;     // [0, 2*16*4096)
    int img = gid >> 16;
    int rem = gid & 65535;
    int b = rem >> 12;
    int p = rem & (HW - 1);
    const float* x = img ? x2 : x1;
    const float* col = x + (size_t)b * 48 * HW + p;
    float v[48]; float s = 0.f;
#pragma unroll
    for (int c = 0; c < 48; ++c) { v[c] = col[c * HW]; s = fmaf(v[c], v[c], s); }
    float r = 1.f / fmaxf(sqrtf(s), 1e-12f);
    rn[(img * BB + b) * HW + p] = r;
    unsigned short* dst = dbp + ((size_t)(img * BB + b) * HW + p) * KHW;
#pragma unroll
    for (int ch = 0; ch < 6; ++ch) {
        union { unsigned u[4]; floatx4 f; } pk;
#pragma unroll
        for (int d = 0; d < 4; ++d) {
            int c = ch * 8 + d * 2;
            pk.u[d] = (unsigned)f2bf(v[c] * r) | ((unsigned)f2bf(v[c + 1] * r) << 16);
        }
        *(floatx4*)(dst + ch * 8) = pk.f;
    }
    floatx4 z = {0.f, 0.f, 0.f, 0.f};
#pragma unroll
    for (int ch = 6; ch < 9; ++ch) *(floatx4*)(dst + ch * 8) = z;  // K-pad zeros
}

// ---------------------------------------------------------------------------
// prep_q: gather + normalize the 2x16x2048 query columns into same layout.
// dir0: queries = x1 cols ids[n]; dir1: queries = x2 cols fp2[n].
// ---------------------------------------------------------------------------
__global__ void prep_q(const float* __restrict__ x1, const float* __restrict__ x2,
                       const float* __restrict__ rn, const int* __restrict__ ids,
                       const int* __restrict__ fp2, unsigned short* __restrict__ qp) {
    int gid = blockIdx.x * 256 + threadIdx.x;     // [0, 2*16*2048)
    int dir = gid >> 15;
    int rem = gid & 32767;
    int b = rem >> 11;
    int n = rem & (NC - 1);
    int img, qcol;
    if (dir == 0) { img = 0; qcol = ids[b * NC + n]; }
    else {
        img = 1;
        int i2 = fp2[b * 2 * NC + n];
        int j2 = fp2[b * 2 * NC + NC + n];
        qcol = i2 * 64 + j2;
    }
    const float* x = img ? x2 : x1;
    const float* col = x + (size_t)b * 48 * HW + qcol;
    float r = rn[(img * BB + b) * HW + qcol];
    unsigned short* dst = qp + ((size_t)(dir * BB + b) * NC + n) * KHW;
#pragma unroll
    for (int ch = 0; ch < 6; ++ch) {
        union { unsigned u[4]; floatx4 f; } pk;
#pragma unroll
        for (int d = 0; d < 4; ++d) {
            int c = ch * 8 + d * 2;
            pk.u[d] = (unsigned)f2bf(col[c * HW] * r) | ((unsigned)f2bf(col[(c + 1) * HW] * r) << 16);
        }
        *(floatx4*)(dst + ch * 8) = pk.f;
    }
    floatx4 z = {0.f, 0.f, 0.f, 0.f};
#pragma unroll
    for (int ch = 6; ch < 9; ++ch) *(floatx4*)(dst + ch * 8) = z;
}

// ---------------------------------------------------------------------------
// maxscore_mfma: masked hardest-negative via MFMA.
// grid = 512: gemm = x&31 (dir = gemm>>4, b = gemm&15)  [XCD: 4 gemms/XCD],
//             mtile = (x>>5)&7 (256 queries), nhalf = x>>8 (2048 db cols).
// Block 256 thr / 4 waves; M_wave = 64 (4 m-tiles of 16); db tiles of 128
// cols DMA'd to LDS (double-buffered, one barrier per tile).
// ---------------------------------------------------------------------------
static __device__ __forceinline__ void dma_tile(const unsigned char* g, unsigned char* l,
                                                int wave, int lane) {
#pragma unroll
    for (int rr = 0; rr < 4; ++rr)
        GLD16(g + rr * 4096 + wave * 1024 + lane * 16, l + rr * 4096 + wave * 1024);
#pragma unroll
    for (int rr = 0; rr < 2; ++rr)
        GLD4(g + 16384 + rr * 1024 + wave * 256 + lane * 4, l + 16384 + rr * 1024 + wave * 256);
}

__global__ __launch_bounds__(256) void maxscore_mfma(
    const unsigned short* __restrict__ dbp, const unsigned short* __restrict__ qp,
    const int* __restrict__ ids, const int* __restrict__ fp2,
    float* __restrict__ maxs2) {
    __shared__ __align__(16) unsigned char smem[36864];   // q slab 36864 / 2 db bufs of 18432

    int tid = threadIdx.x, wave = tid >> 6, lane = tid & 63;
    int quad = lane >> 4, cl = lane & 15;
    int gid = blockIdx.x;
    int gemm = gid & 31, dir = gemm >> 4, b = gemm & 15;
    int rest = gid >> 5, mtile = rest & 7, nhalf = rest >> 3;
    int qbase = mtile * 256;
    int dbimg = 1 - dir;                                  // dir0 db=x2, dir1 db=x1

    // Phase A: DMA this block's 256 queries (256*144 = 36864 B, 9 rounds)
    const unsigned char* qsrc =
        (const unsigned char*)(qp + ((size_t)(dir * BB + b) * NC + qbase) * KHW);
#pragma unroll
    for (int rr = 0; rr < 9; ++rr)
        GLD16(qsrc + rr * 4096 + wave * 1024 + lane * 16, smem + rr * 4096 + wave * 1024);
    __syncthreads();

    // Phase B: A-fragments (A[m=lane&15][k=quad*8+j], k-step = ks*32) + anchors
    short8 afr[4][2];
#pragma unroll
    for (int t = 0; t < 4; ++t) {
        int row = wave * 64 + t * 16 + cl;
#pragma unroll
        for (int ks = 0; ks < 2; ++ks)
            afr[t][ks] = *(const short8*)(smem + row * KB + ks * 64 + quad * 16);
    }
    float qi_f[4][4], qj_f[4][4];
#pragma unroll
    for (int t = 0; t < 4; ++t)
#pragma unroll
        for (int r = 0; r < 4; ++r) {
            int q = qbase + wave * 64 + t * 16 + quad * 4 + r;  // C/D row for this lane
            int qi, qj;
            if (dir == 0) { qi = fp2[b * 2 * NC + q]; qj = fp2[b * 2 * NC + NC + q]; }
            else { int idv = ids[b * NC + q]; qi = idv >> 6; qj = idv & 63; }
            qi_f[t][r] = (float)qi; qj_f[t][r] = (float)qj;
        }
    __syncthreads();   // everyone done with the q slab before db DMA overwrites it

    const unsigned char* dsrc =
        (const unsigned char*)(dbp + ((size_t)(dbimg * BB + b) * HW + nhalf * 2048) * KHW);
    dma_tile(dsrc, smem, wave, lane);                     // prefetch tile 0

    float mx[4][4];
#pragma unroll
    for (int t = 0; t < 4; ++t)
#pragma unroll
        for (int r = 0; r < 4; ++r) mx[t][r] = -1e30f;
    float cl_f = (float)cl;
    float di_f[4][4];

    for (int tile = 0; tile < 16; ++tile) {
        unsigned char* buf = smem + (tile & 1) * 18432;
        __syncthreads();                                  // drains this wave's DMA for buf
        if (tile + 1 < 16)
            dma_tile(dsrc + (tile + 1) * 18432, smem + ((tile + 1) & 1) * 18432, wave, lane);
        int nb_tile = nhalf * 2048 + tile * 128;
#pragma unroll
        for (int sub = 0; sub < 8; ++sub) {
            int nb = nb_tile + sub * 16;
            if ((sub & 3) == 0) {                         // db row changes every 4 subtiles
                float mi_f = (float)(nb >> 6);
#pragma unroll
                for (int t = 0; t < 4; ++t)
#pragma unroll
                    for (int r = 0; r < 4; ++r) di_f[t][r] = qi_f[t][r] - mi_f;
            }
            float mjf = (float)(nb & 63) + cl_f;          // db col for this lane (col=lane&15)
            short8 b0 = *(const short8*)(buf + (sub * 16 + cl) * KB + quad * 16);
            short8 b1 = *(const short8*)(buf + (sub * 16 + cl) * KB + 64 + quad * 16);
#pragma unroll
            for (int t = 0; t < 4; ++t) {
                floatx4 acc = {0.f, 0.f, 0.f, 0.f};
                acc = __builtin_amdgcn_mfma_f32_16x16x32_bf16(
                          __builtin_bit_cast(bf16x8, afr[t][0]),
                          __builtin_bit_cast(bf16x8, b0), acc, 0, 0, 0);
                acc = __builtin_amdgcn_mfma_f32_16x16x32_bf16(
                          __builtin_bit_cast(bf16x8, afr[t][1]),
                          __builtin_bit_cast(bf16x8, b1), acc, 0, 0, 0);
#pragma unroll
                for (int r = 0; r < 4; ++r) {             // 5 VALU per element
                    float dj = qj_f[t][r] - mjf;
                    float ch = fmaxf(fabsf(di_f[t][r]), fabsf(dj));
                    mx[t][r] = (ch > 4.0f) ? fmaxf(mx[t][r], acc[r]) : mx[t][r];
                }
            }
        }
    }

    // reduce max over the 16 lanes of each quad (they hold disjoint col subsets)
#pragma unroll
    for (int t = 0; t < 4; ++t)
#pragma unroll
        for (int r = 0; r < 4; ++r) {
            float v = mx[t][r];
            v = fmaxf(v, __shfl_xor(v, 1, 16));
            v = fmaxf(v, __shfl_xor(v, 2, 16));
            v = fmaxf(v, __shfl_xor(v, 4, 16));
            v = fmaxf(v, __shfl_xor(v, 8, 16));
            mx[t][r] = v;
        }
    if (cl == 0) {
#pragma unroll
        for (int t = 0; t < 4; ++t)
#pragma unroll
            for (int r = 0; r < 4; ++r) {
                int q = qbase + wave * 64 + t * 16 + quad * 4 + r;
                maxs2[((size_t)(nhalf * 32 + dir * BB + b)) * NC + q] = mx[t][r];
            }
    }
}

// ---------------------------------------------------------------------------
// loss: pos-distance (bf16 hi-dot of the two preprocessed query vectors —
// consistent rounding with the neg path), combine 4 max-halves, weighted mean.
// ---------------------------------------------------------------------------
__global__ void loss_kernel(const float* __restrict__ att1, const float* __restrict__ att2,
                            const int* __restrict__ ids, const int* __restrict__ fp2,
                            const unsigned short* __restrict__ qp,
                            const float* __restrict__ maxs2,
                            float* __restrict__ perimg) {
    int b = blockIdx.x, tid = threadIdx.x;
    float num = 0.f, den = 0.f;
    for (int n = tid; n < NC; n += 256) {
        const unsigned short* q0 = qp + ((size_t)(0 * BB + b) * NC + n) * KHW;
        const unsigned short* q1 = qp + ((size_t)(1 * BB + b) * NC + n) * KHW;
        float dot = 0.f;
#pragma unroll
        for (int c = 0; c < 48; ++c) {
            float a = __builtin_bit_cast(float, (unsigned)q0[c] << 16);
            float v = __builtin_bit_cast(float, (unsigned)q1[c] << 16);
            dot = fmaf(a, v, dot);
        }
        float ms = fmaxf(fmaxf(maxs2[(size_t)(0 + b) * NC + n], maxs2[(size_t)(BB + b) * NC + n]),
                         fmaxf(maxs2[(size_t)(32 + b) * NC + n], maxs2[(size_t)(48 + b) * NC + n]));
        float diff = (2.f - 2.f * dot) - (2.f - 2.f * ms);
        int idv = ids[b * NC + n];
        int i2 = fp2[b * 2 * NC + n], j2 = fp2[b * 2 * NC + NC + n];
        float w = att1[b * HW + idv] * att2[b * HW + i2 * 64 + j2];
        num = fmaf(w, fmaxf(0.f, 1.f + diff), num);
        den += w;
    }
    __shared__ float sn[256], sd[256];
    sn[tid] = num; sd[tid] = den;
    __syncthreads();
    for (int s = 128; s > 0; s >>= 1) {
        if (tid < s) { sn[tid] += sn[tid + s]; sd[tid] += sd[tid + s]; }
        __syncthreads();
    }
    if (tid == 0) perimg[b] = sn[0] / sd[0];
}

__global__ void final_kernel(const float* __restrict__ perimg, float* __restrict__ out) {
    float v = (threadIdx.x < BB) ? perimg[threadIdx.x] : 0.f;
#pragma unroll
    for (int off = 32; off > 0; off >>= 1) v += __shfl_down(v, off, 64);
    if (threadIdx.x == 0) out[0] = v * (1.f / BB);
}

extern "C" void kernel_launch(void* const* d_in, const int* in_sizes, int n_in,
                              void* d_out, int out_size, void* d_ws, size_t ws_size,
                              hipStream_t stream) {
    const float* x1  = (const float*)d_in[0];
    const float* x2  = (const float*)d_in[1];
    const float* att1 = (const float*)d_in[2];
    const float* att2 = (const float*)d_in[3];
    const int* ids   = (const int*)d_in[4];
    const int* fp2   = (const int*)d_in[5];
    float* out = (float*)d_out;

    // ws layout (bytes), total ~29.4 MB, fully rewritten every call:
    unsigned char* w = (unsigned char*)d_ws;
    unsigned short* dbp  = (unsigned short*)(w + 0);          // 2*16*4096*144 = 18,874,368
    unsigned short* qpre = (unsigned short*)(w + 18874368);   // 2*16*2048*144 =  9,437,184
    float* rn    = (float*)(w + 28311552);                    // 2*16*4096*4   =    524,288
    float* maxs2 = (float*)(w + 28835840);                    // 2*2*16*2048*4 =    524,288
    float* perimg = (float*)(w + 29360128);                   // 64

    prep_db<<<dim3(512), dim3(256), 0, stream>>>(x1, x2, dbp, rn);
    prep_q<<<dim3(256), dim3(256), 0, stream>>>(x1, x2, rn, ids, fp2, qpre);
    maxscore_mfma<<<dim3(512), dim3(256), 0, stream>>>(dbp, qpre, ids, fp2, maxs2);
    loss_kernel<<<dim3(BB), dim3(256), 0, stream>>>(att1, att2, ids, fp2, qpre, maxs2, perimg);
    final_kernel<<<dim3(1), dim3(64), 0, stream>>>(perimg, out);
}

// Round 3
// 139.000 us; speedup vs baseline: 5.0459x; 1.4305x over previous
//
#include <hip/hip_runtime.h>
#include <stdint.h>

// Problem constants: B=16, C=48, H=W=64, N_CORR=2048
#define BB 16
#define HW 4096
#define NC 2048
#define KHW 72           // halfwords per column: 48 data + 16 zeros (K-pad to 64) + 8 pad
#define KB 144           // bytes per column (16B-aligned)

typedef __attribute__((ext_vector_type(8))) __bf16 bf16x8;
typedef __attribute__((ext_vector_type(8))) short short8;
typedef __attribute__((ext_vector_type(4))) float floatx4;

static __device__ __forceinline__ unsigned short f2bf(float f) {
    unsigned u = __builtin_bit_cast(unsigned, f);
    unsigned r = u + 0x7fffu + ((u >> 16) & 1u);    // RNE
    return (unsigned short)(r >> 16);
}

#define GLD16(g, l) __builtin_amdgcn_global_load_lds((const __attribute__((address_space(1))) void*)(g), (__attribute__((address_space(3))) void*)(l), 16, 0, 0)
#define GLD4(g, l)  __builtin_amdgcn_global_load_lds((const __attribute__((address_space(1))) void*)(g), (__attribute__((address_space(3))) void*)(l), 4, 0, 0)

// ---------------------------------------------------------------------------
// prep_db: normalize every column of x1,x2 to bf16, K-padded, stride 144B.
// ---------------------------------------------------------------------------
__global__ void prep_db(const float* __restrict__ x1, const float* __restrict__ x2,
                        unsigned short* __restrict__ dbp) {
    int gid = blockIdx.x * 256 + threadIdx.x;     // [0, 2*16*4096)
    int img = gid >> 16;
    int rem = gid & 65535;
    int b = rem >> 12;
    int p = rem & (HW - 1);
    const float* x = img ? x2 : x1;
    const float* col = x + (size_t)b * 48 * HW + p;
    float v[48]; float s = 0.f;
#pragma unroll
    for (int c = 0; c < 48; ++c) { v[c] = col[c * HW]; s = fmaf(v[c], v[c], s); }
    float r = 1.f / fmaxf(sqrtf(s), 1e-12f);
    unsigned short* dst = dbp + ((size_t)(img * BB + b) * HW + p) * KHW;
#pragma unroll
    for (int ch = 0; ch < 6; ++ch) {
        union { unsigned u[4]; floatx4 f; } pk;
#pragma unroll
        for (int d = 0; d < 4; ++d) {
            int c = ch * 8 + d * 2;
            pk.u[d] = (unsigned)f2bf(v[c] * r) | ((unsigned)f2bf(v[c + 1] * r) << 16);
        }
        *(floatx4*)(dst + ch * 8) = pk.f;
    }
    floatx4 z = {0.f, 0.f, 0.f, 0.f};
#pragma unroll
    for (int ch = 6; ch < 9; ++ch) *(floatx4*)(dst + ch * 8) = z;  // K-pad zeros
}

// ---------------------------------------------------------------------------
// sortq: counting sort of each (dir,b) segment's 2048 queries by anchor row qi.
// Outputs per sorted slot: perm (orig index), qcol_s (query's feature column),
// aqpack (qi<<8 | qj anchor). 32 blocks (one per segment).
// ---------------------------------------------------------------------------
__global__ void sortq_kernel(const int* __restrict__ ids, const int* __restrict__ fp2,
                             int* __restrict__ perm, int* __restrict__ qcol_s,
                             int* __restrict__ aqpack) {
    int seg = blockIdx.x;            // dir*16 + b
    int dir = seg >> 4, b = seg & 15;
    int tid = threadIdx.x;
    __shared__ int hist[64], base[64];
    if (tid < 64) hist[tid] = 0;
    __syncthreads();
#pragma unroll
    for (int k = 0; k < 8; ++k) {
        int n = k * 256 + tid;
        int idv = ids[b * NC + n];
        int i2 = fp2[b * 2 * NC + n];
        int qi = (dir == 0) ? i2 : (idv >> 6);
        atomicAdd(&hist[qi], 1);
    }
    __syncthreads();
    if (tid == 0) {
        int run = 0;
        for (int k = 0; k < 64; ++k) { base[k] = run; run += hist[k]; }
    }
    __syncthreads();
#pragma unroll
    for (int k = 0; k < 8; ++k) {
        int n = k * 256 + tid;
        int idv = ids[b * NC + n];
        int i2 = fp2[b * 2 * NC + n];
        int j2 = fp2[b * 2 * NC + NC + n];
        int qi, qj, qcol;
        if (dir == 0) { qi = i2; qj = j2; qcol = idv; }
        else          { qi = idv >> 6; qj = idv & 63; qcol = i2 * 64 + j2; }
        int slot = atomicAdd(&base[qi], 1);
        perm[seg * NC + slot] = n;
        qcol_s[seg * NC + slot] = qcol;
        aqpack[seg * NC + slot] = (qi << 8) | qj;
    }
}

// ---------------------------------------------------------------------------
// maxscore_mfma: masked hardest-negative via MFMA, qi-sorted queries.
// grid = 1024: gemm = gid&31 (seg), mtile = (gid>>5)&7, nquarter = gid>>8.
// Per block: 256 sorted queries x 1024 db cols. db tiles of 128 cols DMA'd
// to LDS (double-buffered). A-frags gathered directly from dbp (L2-hot).
// Result merged across quarters via atomicMax on monotone-encoded dot+2.
// ---------------------------------------------------------------------------
static __device__ __forceinline__ void dma_tile(const unsigned char* g, unsigned char* l,
                                                int wave, int lane) {
#pragma unroll
    for (int rr = 0; rr < 4; ++rr)
        GLD16(g + rr * 4096 + wave * 1024 + lane * 16, l + rr * 4096 + wave * 1024);
#pragma unroll
    for (int rr = 0; rr < 2; ++rr)
        GLD4(g + 16384 + rr * 1024 + wave * 256 + lane * 4, l + 16384 + rr * 1024 + wave * 256);
}

__global__ __launch_bounds__(256, 4) void maxscore_mfma(
    const unsigned short* __restrict__ dbp,
    const int* __restrict__ perm, const int* __restrict__ qcol_s,
    const int* __restrict__ aqpack, unsigned int* __restrict__ maxs2enc) {
    __shared__ __align__(16) unsigned char smem[36864];   // 2 db buffers of 18432

    int tid = threadIdx.x, wave = tid >> 6, lane = tid & 63;
    int quad = lane >> 4, cl = lane & 15;
    int gid = blockIdx.x;
    int seg = gid & 31, dir = seg >> 4, b = seg & 15;
    int rest = gid >> 5, mtile = rest & 7, nq = rest >> 3;
    int qbase = mtile * 256;
    int dbimg = 1 - dir;

    // A-fragments: gather 16B loads straight from dbp (query image = dir)
    const unsigned char* dbQ = (const unsigned char*)(dbp + (size_t)(dir * BB + b) * HW * KHW);
    short8 afr[4][2];
#pragma unroll
    for (int t = 0; t < 4; ++t) {
        int slot = qbase + wave * 64 + t * 16 + cl;       // A[m=lane&15]
        int qc = qcol_s[seg * NC + slot];
        const unsigned char* src = dbQ + (size_t)qc * KB;
        afr[t][0] = *(const short8*)(src + quad * 16);
        afr[t][1] = *(const short8*)(src + 64 + quad * 16);
    }
    // Anchors for this lane's C/D rows (row = quad*4+r)
    float qif[4][4], qjc[4][4];
    float cl_f = (float)cl;
#pragma unroll
    for (int t = 0; t < 4; ++t)
#pragma unroll
        for (int r = 0; r < 4; ++r) {
            int slot = qbase + wave * 64 + t * 16 + quad * 4 + r;
            int ap = aqpack[seg * NC + slot];
            qif[t][r] = (float)(ap >> 8);
            qjc[t][r] = (float)(ap & 255) - cl_f;         // qj - lane col offset
        }
    // Wave's sorted qi range (sorted ascending within segment)
    int wb = seg * NC + qbase + wave * 64;
    int qimin = __builtin_amdgcn_readfirstlane(aqpack[wb] >> 8);
    int qimax = __builtin_amdgcn_readfirstlane(aqpack[wb + 63] >> 8);

    const unsigned char* dsrc =
        (const unsigned char*)(dbp + ((size_t)(dbimg * BB + b) * HW + nq * 1024) * KHW);
    dma_tile(dsrc, smem, wave, lane);                     // prefetch tile 0

    const floatx4 zf = {0.f, 0.f, 0.f, 0.f};              // persistent zero C operand
    float mx[4][4];
#pragma unroll
    for (int t = 0; t < 4; ++t)
#pragma unroll
        for (int r = 0; r < 4; ++r) mx[t][r] = -1e30f;

    for (int tile = 0; tile < 8; ++tile) {
        unsigned char* buf = smem + (tile & 1) * 18432;
        __syncthreads();
        if (tile + 1 < 8)
            dma_tile(dsrc + (tile + 1) * 18432, smem + ((tile + 1) & 1) * 18432, wave, lane);
        int mi0 = (nq * 1024 + tile * 128) >> 6;          // even; half adds 0/1
#pragma unroll
        for (int half = 0; half < 2; ++half) {
            int mi = mi0 + half;
            bool active = (mi >= qimin - 4) && (mi <= qimax + 4);   // wave-uniform
            if (active) {
                float mi_f = (float)mi;
                bool rowok[4][4];
#pragma unroll
                for (int t = 0; t < 4; ++t)
#pragma unroll
                    for (int r = 0; r < 4; ++r)
                        rowok[t][r] = fabsf(qif[t][r] - mi_f) > 4.0f;
#pragma unroll
                for (int js = 0; js < 4; ++js) {
                    int sub = half * 4 + js;
                    float jj = (float)(js * 16);
                    short8 b0 = *(const short8*)(buf + (sub * 16 + cl) * KB + quad * 16);
                    short8 b1 = *(const short8*)(buf + (sub * 16 + cl) * KB + 64 + quad * 16);
#pragma unroll
                    for (int t = 0; t < 4; ++t) {
                        floatx4 acc = __builtin_amdgcn_mfma_f32_16x16x32_bf16(
                            __builtin_bit_cast(bf16x8, afr[t][0]),
                            __builtin_bit_cast(bf16x8, b0), zf, 0, 0, 0);
                        acc = __builtin_amdgcn_mfma_f32_16x16x32_bf16(
                            __builtin_bit_cast(bf16x8, afr[t][1]),
                            __builtin_bit_cast(bf16x8, b1), acc, 0, 0, 0);
#pragma unroll
                        for (int r = 0; r < 4; ++r) {
                            float dj = qjc[t][r] - jj;
                            bool ok = rowok[t][r] || (fabsf(dj) > 4.0f);
                            mx[t][r] = ok ? fmaxf(mx[t][r], acc[r]) : mx[t][r];
                        }
                    }
                }
            } else {                                      // all rows allowed: 1 op/elem
#pragma unroll
                for (int js = 0; js < 4; ++js) {
                    int sub = half * 4 + js;
                    short8 b0 = *(const short8*)(buf + (sub * 16 + cl) * KB + quad * 16);
                    short8 b1 = *(const short8*)(buf + (sub * 16 + cl) * KB + 64 + quad * 16);
#pragma unroll
                    for (int t = 0; t < 4; ++t) {
                        floatx4 acc = __builtin_amdgcn_mfma_f32_16x16x32_bf16(
                            __builtin_bit_cast(bf16x8, afr[t][0]),
                            __builtin_bit_cast(bf16x8, b0), zf, 0, 0, 0);
                        acc = __builtin_amdgcn_mfma_f32_16x16x32_bf16(
                            __builtin_bit_cast(bf16x8, afr[t][1]),
                            __builtin_bit_cast(bf16x8, b1), acc, 0, 0, 0);
#pragma unroll
                        for (int r = 0; r < 4; ++r)
                            mx[t][r] = fmaxf(mx[t][r], acc[r]);
                    }
                }
            }
        }
    }

    // reduce max over the 16 lanes of each quad (disjoint col subsets)
#pragma unroll
    for (int t = 0; t < 4; ++t)
#pragma unroll
        for (int r = 0; r < 4; ++r) {
            float v = mx[t][r];
            v = fmaxf(v, __shfl_xor(v, 1, 16));
            v = fmaxf(v, __shfl_xor(v, 2, 16));
            v = fmaxf(v, __shfl_xor(v, 4, 16));
            v = fmaxf(v, __shfl_xor(v, 8, 16));
            mx[t][r] = v;
        }
    if (cl == 0) {
#pragma unroll
        for (int t = 0; t < 4; ++t)
#pragma unroll
            for (int r = 0; r < 4; ++r) {
                int slot = qbase + wave * 64 + t * 16 + quad * 4 + r;
                int orig = perm[seg * NC + slot];
                float v = mx[t][r] + 2.0f;                // > 0: uint-monotone
                atomicMax(&maxs2enc[(size_t)seg * NC + orig],
                          __builtin_bit_cast(unsigned, v));
            }
    }
}

// ---------------------------------------------------------------------------
// loss: pos-distance from dbp bf16 columns (consistent rounding with neg
// path), decode/merge the two direction maxes, weighted partial sums.
// grid = 128 (8 chunks x 16 images).
// ---------------------------------------------------------------------------
__global__ void loss_kernel(const float* __restrict__ att1, const float* __restrict__ att2,
                            const int* __restrict__ ids, const int* __restrict__ fp2,
                            const unsigned short* __restrict__ dbp,
                            const unsigned int* __restrict__ maxs2enc,
                            float* __restrict__ pnum, float* __restrict__ pden) {
    int b = blockIdx.x >> 3, chunk = blockIdx.x & 7;
    int tid = threadIdx.x;
    int n = chunk * 256 + tid;
    int idv = ids[b * NC + n];
    int i2 = fp2[b * 2 * NC + n], j2 = fp2[b * 2 * NC + NC + n];
    const uint4* a4 = (const uint4*)(dbp + ((size_t)(0 * BB + b) * HW + idv) * KHW);
    const uint4* b4 = (const uint4*)(dbp + ((size_t)(1 * BB + b) * HW + i2 * 64 + j2) * KHW);
    float dot = 0.f;
#pragma unroll
    for (int i = 0; i < 6; ++i) {
        uint4 xa = a4[i], xb = b4[i];
        const unsigned* xu = (const unsigned*)&xa;
        const unsigned* yu = (const unsigned*)&xb;
#pragma unroll
        for (int w = 0; w < 4; ++w) {
            float xl = __builtin_bit_cast(float, xu[w] << 16);
            float xh = __builtin_bit_cast(float, xu[w] & 0xffff0000u);
            float yl = __builtin_bit_cast(float, yu[w] << 16);
            float yh = __builtin_bit_cast(float, yu[w] & 0xffff0000u);
            dot = fmaf(xl, yl, fmaf(xh, yh, dot));
        }
    }
    float m0 = __builtin_bit_cast(float, maxs2enc[(size_t)(0 * BB + b) * NC + n]) - 2.0f;
    float m1 = __builtin_bit_cast(float, maxs2enc[(size_t)(1 * BB + b) * NC + n]) - 2.0f;
    float ms = fmaxf(m0, m1);
    float diff = (2.f - 2.f * dot) - (2.f - 2.f * ms);
    float w = att1[b * HW + idv] * att2[b * HW + i2 * 64 + j2];
    float num = w * fmaxf(0.f, 1.f + diff);
    float den = w;
    __shared__ float sn[256], sd[256];
    sn[tid] = num; sd[tid] = den;
    __syncthreads();
    for (int s = 128; s > 0; s >>= 1) {
        if (tid < s) { sn[tid] += sn[tid + s]; sd[tid] += sd[tid + s]; }
        __syncthreads();
    }
    if (tid == 0) { pnum[blockIdx.x] = sn[0]; pden[blockIdx.x] = sd[0]; }
}

__global__ void final_kernel(const float* __restrict__ pnum, const float* __restrict__ pden,
                             float* __restrict__ out) {
    int tid = threadIdx.x;
    __shared__ float r[16];
    if (tid < 16) {
        float n = 0.f, d = 0.f;
#pragma unroll
        for (int c = 0; c < 8; ++c) { n += pnum[tid * 8 + c]; d += pden[tid * 8 + c]; }
        r[tid] = n / d;
    }
    __syncthreads();
    if (tid == 0) {
        float s = 0.f;
#pragma unroll
        for (int k = 0; k < 16; ++k) s += r[k];
        out[0] = s * (1.f / BB);
    }
}

extern "C" void kernel_launch(void* const* d_in, const int* in_sizes, int n_in,
                              void* d_out, int out_size, void* d_ws, size_t ws_size,
                              hipStream_t stream) {
    const float* x1  = (const float*)d_in[0];
    const float* x2  = (const float*)d_in[1];
    const float* att1 = (const float*)d_in[2];
    const float* att2 = (const float*)d_in[3];
    const int* ids   = (const int*)d_in[4];
    const int* fp2   = (const int*)d_in[5];
    float* out = (float*)d_out;

    // ws layout (bytes), total ~19.9 MB, fully rewritten every call:
    unsigned char* w = (unsigned char*)d_ws;
    unsigned short* dbp = (unsigned short*)(w + 0);          // 2*16*4096*144 = 18,874,368
    int* perm    = (int*)(w + 18874368);                     // 32*2048*4 = 262,144
    int* qcol_s  = (int*)(w + 19136512);                     // 262,144
    int* aqpack  = (int*)(w + 19398656);                     // 262,144
    unsigned int* maxs2enc = (unsigned int*)(w + 19660800);  // 262,144
    float* pnum  = (float*)(w + 19922944);                   // 512
    float* pden  = (float*)(w + 19923456);                   // 512

    prep_db<<<dim3(512), dim3(256), 0, stream>>>(x1, x2, dbp);
    sortq_kernel<<<dim3(32), dim3(256), 0, stream>>>(ids, fp2, perm, qcol_s, aqpack);
    hipMemsetAsync(maxs2enc, 0, 32 * NC * sizeof(unsigned int), stream);
    maxscore_mfma<<<dim3(1024), dim3(256), 0, stream>>>(dbp, perm, qcol_s, aqpack, maxs2enc);
    loss_kernel<<<dim3(128), dim3(256), 0, stream>>>(att1, att2, ids, fp2, dbp, maxs2enc, pnum, pden);
    final_kernel<<<dim3(1), dim3(64), 0, stream>>>(pnum, pden, out);
}